// Round 1
// baseline (2316.490 us; speedup 1.0000x reference)
//
#include <hip/hip_runtime.h>

constexpr int NFEAT = 1024;
constexpr int HID   = 64;
constexpr int NC    = 16;

// ---------------- CSR build ----------------

__global__ __launch_bounds__(256) void k_hist(const int* __restrict__ rows, int* __restrict__ deg, int e) {
  int i = blockIdx.x * 256 + threadIdx.x;
  if (i < e) atomicAdd(&deg[rows[i]], 1);
}

// exclusive scan of chunks of 2048; block sums to bsum (if non-null)
__global__ __launch_bounds__(256) void k_scan1(const int* __restrict__ in, int* __restrict__ out,
                                               int* __restrict__ bsum, int n) {
  __shared__ int sh[256];
  int base = blockIdx.x * 2048 + threadIdx.x * 8;
  int v[8]; int s = 0;
#pragma unroll
  for (int j = 0; j < 8; ++j) { int idx = base + j; v[j] = (idx < n) ? in[idx] : 0; s += v[j]; }
  sh[threadIdx.x] = s; __syncthreads();
  for (int off = 1; off < 256; off <<= 1) {
    int x = (threadIdx.x >= off) ? sh[threadIdx.x - off] : 0;
    __syncthreads();
    sh[threadIdx.x] += x;
    __syncthreads();
  }
  int run = (threadIdx.x > 0) ? sh[threadIdx.x - 1] : 0;
  if (bsum != nullptr && threadIdx.x == 255) bsum[blockIdx.x] = sh[255];
#pragma unroll
  for (int j = 0; j < 8; ++j) { int idx = base + j; if (idx < n) out[idx] = run; run += v[j]; }
}

__global__ __launch_bounds__(256) void k_scanadd(int* __restrict__ rp, int* __restrict__ pos,
                                                 const int* __restrict__ bs, int n) {
  int i = blockIdx.x * 256 + threadIdx.x;
  if (i < n) { int v = rp[i] + bs[i >> 11]; rp[i] = v; pos[i] = v; }
}

__global__ __launch_bounds__(256) void k_scatter(const int* __restrict__ rows, const int* __restrict__ cols,
                                                 const float* __restrict__ vals, int* __restrict__ pos,
                                                 int* __restrict__ oc, float* __restrict__ ov, int e) {
  int i = blockIdx.x * 256 + threadIdx.x;
  if (i < e) {
    int r = rows[i];
    int p = atomicAdd(&pos[r], 1);
    oc[p] = cols[i];
    ov[p] = vals[i];
  }
}

// ---------------- fused embed GEMM + 112-wide projection ----------------
// T layout (contiguous floats from T base): t0[N*16] t1[N*16] t2[N*16] U1[N*32] U2[N*32]
// U1 = [t3 | t5], U2 = [t4 | t6]
__global__ __launch_bounds__(256) void k_embed(const float* __restrict__ x, const float* __restrict__ we,
                                               const float* __restrict__ wcl, float* __restrict__ T, int n) {
  __shared__ float pool[7168];   // phase1: xs[32][68] + ws[32][68]; phase2: wall[64][112] (permuted)
  __shared__ float rs[64 * 68];
  float* xs  = pool;
  float* wsm = pool + 32 * 68;

  const int t  = threadIdx.x;
  const int tx = t & 15, ty = t >> 4;
  const int br = blockIdx.x * 64;

  const int sr  = t >> 2;           // staging row 0..63
  const int skc = (t & 3) * 8;      // staging k offset
  const int xrow = min(br + sr, n - 1);
  const float* xp = x + (size_t)xrow * NFEAT;
  const int wk  = t >> 3;           // 0..31
  const int wc8 = (t & 7) * 8;

  float acc[4][4] = {};
  for (int k0 = 0; k0 < NFEAT; k0 += 32) {
    float4 xa = *(const float4*)(xp + k0 + skc);
    float4 xb = *(const float4*)(xp + k0 + skc + 4);
    float4 wa = *(const float4*)(we + (size_t)(k0 + wk) * HID + wc8);
    float4 wb = *(const float4*)(we + (size_t)(k0 + wk) * HID + wc8 + 4);
    __syncthreads();
    xs[(skc + 0) * 68 + sr] = xa.x;
    xs[(skc + 1) * 68 + sr] = xa.y;
    xs[(skc + 2) * 68 + sr] = xa.z;
    xs[(skc + 3) * 68 + sr] = xa.w;
    xs[(skc + 4) * 68 + sr] = xb.x;
    xs[(skc + 5) * 68 + sr] = xb.y;
    xs[(skc + 6) * 68 + sr] = xb.z;
    xs[(skc + 7) * 68 + sr] = xb.w;
    *(float4*)&wsm[wk * 68 + wc8]     = wa;
    *(float4*)&wsm[wk * 68 + wc8 + 4] = wb;
    __syncthreads();
#pragma unroll
    for (int kk = 0; kk < 32; ++kk) {
      float4 a = *(const float4*)&xs[kk * 68 + ty * 4];
      float4 b = *(const float4*)&wsm[kk * 68 + tx * 4];
      acc[0][0] += a.x * b.x; acc[0][1] += a.x * b.y; acc[0][2] += a.x * b.z; acc[0][3] += a.x * b.w;
      acc[1][0] += a.y * b.x; acc[1][1] += a.y * b.y; acc[1][2] += a.y * b.z; acc[1][3] += a.y * b.w;
      acc[2][0] += a.z * b.x; acc[2][1] += a.z * b.y; acc[2][2] += a.z * b.z; acc[2][3] += a.z * b.w;
      acc[3][0] += a.w * b.x; acc[3][1] += a.w * b.y; acc[3][2] += a.w * b.z; acc[3][3] += a.w * b.w;
    }
  }
  __syncthreads();   // done with xs/wsm; pool gets reused for wall

  // relu -> rs
#pragma unroll
  for (int i = 0; i < 4; ++i) {
    float4 r4;
    r4.x = fmaxf(acc[i][0], 0.f);
    r4.y = fmaxf(acc[i][1], 0.f);
    r4.z = fmaxf(acc[i][2], 0.f);
    r4.w = fmaxf(acc[i][3], 0.f);
    *(float4*)&rs[(ty * 4 + i) * 68 + tx * 4] = r4;
  }
  // wall load, permuted block order [t0 t1 t2 t3 t5 t4 t6]
  const int srcblk[7] = {0, 1, 2, 3, 5, 4, 6};
  for (int i = t; i < 7168; i += 256) {
    int k = i / 112, c = i % 112;
    int p = c >> 4, cc = c & 15;
    pool[i] = wcl[(size_t)(64 * srcblk[p] + k) * NC + cc];
  }
  __syncthreads();

  // projection: thread -> row = t>>2, colgroup pcg = t&3 (28 permuted cols)
  const int prow = t >> 2, pcg = t & 3;
  float4 ap[7];
#pragma unroll
  for (int j = 0; j < 7; ++j) ap[j] = make_float4(0.f, 0.f, 0.f, 0.f);
  for (int k = 0; k < 64; ++k) {
    float rv = rs[prow * 68 + k];
#pragma unroll
    for (int j = 0; j < 7; ++j) {
      float4 w4 = *(const float4*)&pool[k * 112 + pcg * 28 + j * 4];
      ap[j].x += rv * w4.x; ap[j].y += rv * w4.y; ap[j].z += rv * w4.z; ap[j].w += rv * w4.w;
    }
  }
  int gr = br + prow;
  if (gr < n) {
    size_t sn = (size_t)n;
#pragma unroll
    for (int j = 0; j < 7; ++j) {
      int c = pcg * 28 + j * 4;
      int p = c >> 4, cc = c & 15;
      size_t o;
      if (p < 3)      o = (size_t)p * 16 * sn + (size_t)gr * 16 + cc;
      else if (p < 5) o = 48 * sn + (size_t)gr * 32 + ((p == 4) ? 16 : 0) + cc;
      else            o = 80 * sn + (size_t)gr * 32 + ((p == 6) ? 16 : 0) + cc;
      *(float4*)(T + o) = ap[j];
    }
  }
}

// ---------------- CSR SpMM, width = 4*L floats, L lanes per row ----------------
template <int L>
__global__ __launch_bounds__(256) void k_spmm(const int* __restrict__ rp, const int* __restrict__ re,
                                              const int* __restrict__ cols, const float* __restrict__ vals,
                                              const float* __restrict__ src, float* __restrict__ dst, int n) {
  int t = blockIdx.x * 256 + threadIdx.x;
  int row = t / L;
  if (row >= n) return;
  int sub = t % L;
  int e = rp[row], end = re[row];
  const float4* s4 = (const float4*)src;
  float4 acc = make_float4(0.f, 0.f, 0.f, 0.f);
  for (; e < end; ++e) {
    int c = cols[e];
    float v = vals[e];
    float4 g = s4[(size_t)c * L + sub];
    acc.x += v * g.x; acc.y += v * g.y; acc.z += v * g.z; acc.w += v * g.w;
  }
  ((float4*)dst)[(size_t)row * L + sub] = acc;
}

// ---------------- combine: t1 += P1.lo + P2.lo ; t2 += P1.hi + P2.hi ----------------
__global__ __launch_bounds__(256) void k_combine(float* __restrict__ t1, float* __restrict__ t2,
                                                 const float* __restrict__ P1, const float* __restrict__ P2,
                                                 int n) {
  int t = blockIdx.x * 256 + threadIdx.x;
  if (t >= n * 4) return;
  int row = t >> 2, c = t & 3;
  float4* T1 = (float4*)t1;
  float4* T2 = (float4*)t2;
  const float4* p1 = (const float4*)P1;
  const float4* p2 = (const float4*)P2;
  float4 a = T1[t], u = p1[(size_t)row * 8 + c], w = p2[(size_t)row * 8 + c];
  a.x += u.x + w.x; a.y += u.y + w.y; a.z += u.z + w.z; a.w += u.w + w.w;
  T1[t] = a;
  float4 b = T2[t];
  u = p1[(size_t)row * 8 + 4 + c]; w = p2[(size_t)row * 8 + 4 + c];
  b.x += u.x + w.x; b.y += u.y + w.y; b.z += u.z + w.z; b.w += u.w + w.w;
  T2[t] = b;
}

// ---------------- final: out = log_softmax(t0 + zA + zB) ----------------
__global__ __launch_bounds__(256) void k_final(const float* __restrict__ t0, const float* __restrict__ zA,
                                               const float* __restrict__ zB, float* __restrict__ out, int n) {
  int row = blockIdx.x * 256 + threadIdx.x;
  if (row >= n) return;
  const float4* a4 = (const float4*)t0;
  const float4* b4 = (const float4*)zA;
  const float4* c4 = (const float4*)zB;
  float z[16];
#pragma unroll
  for (int j = 0; j < 4; ++j) {
    float4 a = a4[(size_t)row * 4 + j], b = b4[(size_t)row * 4 + j], c = c4[(size_t)row * 4 + j];
    z[j * 4 + 0] = a.x + b.x + c.x;
    z[j * 4 + 1] = a.y + b.y + c.y;
    z[j * 4 + 2] = a.z + b.z + c.z;
    z[j * 4 + 3] = a.w + b.w + c.w;
  }
  float m = z[0];
#pragma unroll
  for (int i = 1; i < 16; ++i) m = fmaxf(m, z[i]);
  float s = 0.f;
#pragma unroll
  for (int i = 0; i < 16; ++i) s += expf(z[i] - m);
  float lg = m + logf(s);
  float4* o4 = (float4*)out;
#pragma unroll
  for (int j = 0; j < 4; ++j) {
    float4 o;
    o.x = z[j * 4 + 0] - lg; o.y = z[j * 4 + 1] - lg;
    o.z = z[j * 4 + 2] - lg; o.w = z[j * 4 + 3] - lg;
    o4[(size_t)row * 4 + j] = o;
  }
}

extern "C" void kernel_launch(void* const* d_in, const int* in_sizes, int n_in,
                              void* d_out, int out_size, void* d_ws, size_t ws_size,
                              hipStream_t stream) {
  const float* x   = (const float*)d_in[0];
  const int*   a1i = (const int*)d_in[1];
  const float* a1v = (const float*)d_in[2];
  const int*   a2i = (const int*)d_in[3];
  const float* a2v = (const float*)d_in[4];
  const float* we  = (const float*)d_in[5];
  const float* wcl = (const float*)d_in[6];
  float* out = (float*)d_out;

  const int n  = in_sizes[0] / NFEAT;
  const int e1 = in_sizes[2];
  const int e2 = in_sizes[4];

  char* ws = (char*)d_ws;
  size_t off = 0;
  auto alloc = [&](size_t bytes) -> void* {
    void* p = ws + off;
    off += (bytes + 255) & ~(size_t)255;
    return p;
  };
  // T block must be contiguous: t0,t1,t2,U1,U2 (all sizes are multiples of 256B)
  float* t0 = (float*)alloc((size_t)n * 16 * 4);
  float* t1 = (float*)alloc((size_t)n * 16 * 4);
  float* t2 = (float*)alloc((size_t)n * 16 * 4);
  float* U1 = (float*)alloc((size_t)n * 32 * 4);
  float* U2 = (float*)alloc((size_t)n * 32 * 4);
  float* P1 = (float*)alloc((size_t)n * 32 * 4);
  float* P2 = (float*)alloc((size_t)n * 32 * 4);
  int* deg1 = (int*)alloc((size_t)n * 4);
  int* rp1  = (int*)alloc((size_t)n * 4);
  int* pos1 = (int*)alloc((size_t)n * 4);
  int* deg2 = (int*)alloc((size_t)n * 4);
  int* rp2  = (int*)alloc((size_t)n * 4);
  int* pos2 = (int*)alloc((size_t)n * 4);
  int*   col1 = (int*)alloc((size_t)e1 * 4);
  float* val1 = (float*)alloc((size_t)e1 * 4);
  int*   col2 = (int*)alloc((size_t)e2 * 4);
  float* val2 = (float*)alloc((size_t)e2 * 4);
  int* bs1  = (int*)alloc(1024);
  int* bsx1 = (int*)alloc(1024);
  int* bs2  = (int*)alloc(1024);
  int* bsx2 = (int*)alloc(1024);
  float* zA = U1;  // U1/U2 dead after inner spmm passes
  float* zB = U2;

  (void)ws_size; (void)n_in; (void)out_size;

  hipMemsetAsync(deg1, 0, (size_t)n * 4, stream);
  hipMemsetAsync(deg2, 0, (size_t)n * 4, stream);

  k_hist<<<(e1 + 255) / 256, 256, 0, stream>>>(a1i, deg1, e1);
  k_hist<<<(e2 + 255) / 256, 256, 0, stream>>>(a2i, deg2, e2);

  int nchunk = (n + 2047) / 2048;
  k_scan1<<<nchunk, 256, 0, stream>>>(deg1, rp1, bs1, n);
  k_scan1<<<nchunk, 256, 0, stream>>>(deg2, rp2, bs2, n);
  k_scan1<<<1, 256, 0, stream>>>(bs1, bsx1, nullptr, nchunk);
  k_scan1<<<1, 256, 0, stream>>>(bs2, bsx2, nullptr, nchunk);
  k_scanadd<<<(n + 255) / 256, 256, 0, stream>>>(rp1, pos1, bsx1, n);
  k_scanadd<<<(n + 255) / 256, 256, 0, stream>>>(rp2, pos2, bsx2, n);

  k_scatter<<<(e1 + 255) / 256, 256, 0, stream>>>(a1i, a1i + e1, a1v, pos1, col1, val1, e1);
  k_scatter<<<(e2 + 255) / 256, 256, 0, stream>>>(a2i, a2i + e2, a2v, pos2, col2, val2, e2);

  k_embed<<<(n + 63) / 64, 256, 0, stream>>>(x, we, wcl, t0, n);

  // inner passes: P1 = A1 @ [t3|t5], P2 = A2 @ [t4|t6]   (width 32)
  k_spmm<8><<<(n * 8 + 255) / 256, 256, 0, stream>>>(rp1, pos1, col1, val1, U1, P1, n);
  k_spmm<8><<<(n * 8 + 255) / 256, 256, 0, stream>>>(rp2, pos2, col2, val2, U2, P2, n);

  // p -> t1 (in place), q -> t2 (in place)
  k_combine<<<(n * 4 + 255) / 256, 256, 0, stream>>>(t1, t2, P1, P2, n);

  // outer passes: zA = A1 @ p, zB = A2 @ q   (width 16)
  k_spmm<4><<<(n * 4 + 255) / 256, 256, 0, stream>>>(rp1, pos1, col1, val1, t1, zA, n);
  k_spmm<4><<<(n * 4 + 255) / 256, 256, 0, stream>>>(rp2, pos2, col2, val2, t2, zB, n);

  k_final<<<(n + 255) / 256, 256, 0, stream>>>(t0, zA, zB, out, n);
}

// Round 2
// 1741.946 us; speedup vs baseline: 1.3298x; 1.3298x over previous
//
#include <hip/hip_runtime.h>

constexpr int NFEAT = 1024;
constexpr int HID   = 64;
constexpr int NC    = 16;

// ---------------- degree histogram ----------------
__global__ __launch_bounds__(256) void k_hist(const int* __restrict__ rows, int* __restrict__ deg, int e) {
  int i = blockIdx.x * 256 + threadIdx.x;
  if (i < e) atomicAdd(&deg[rows[i]], 1);
}

// exclusive scan of chunks of 2048; block sums to bsum (if non-null)
__global__ __launch_bounds__(256) void k_scan1(const int* __restrict__ in, int* __restrict__ out,
                                               int* __restrict__ bsum, int n) {
  __shared__ int sh[256];
  int base = blockIdx.x * 2048 + threadIdx.x * 8;
  int v[8]; int s = 0;
#pragma unroll
  for (int j = 0; j < 8; ++j) { int idx = base + j; v[j] = (idx < n) ? in[idx] : 0; s += v[j]; }
  sh[threadIdx.x] = s; __syncthreads();
  for (int off = 1; off < 256; off <<= 1) {
    int x = (threadIdx.x >= off) ? sh[threadIdx.x - off] : 0;
    __syncthreads();
    sh[threadIdx.x] += x;
    __syncthreads();
  }
  int run = (threadIdx.x > 0) ? sh[threadIdx.x - 1] : 0;
  if (bsum != nullptr && threadIdx.x == 255) bsum[blockIdx.x] = sh[255];
#pragma unroll
  for (int j = 0; j < 8; ++j) { int idx = base + j; if (idx < n) out[idx] = run; run += v[j]; }
}

__global__ __launch_bounds__(256) void k_scanadd(int* __restrict__ rp, const int* __restrict__ bs, int n) {
  int i = blockIdx.x * 256 + threadIdx.x;
  if (i < n) rp[i] += bs[i >> 11];
}

// d = deg > 0 ? deg^-1/2 : 0
__global__ __launch_bounds__(256) void k_rsqrt(const int* __restrict__ deg1, const int* __restrict__ deg2,
                                               float* __restrict__ d1, float* __restrict__ d2, int n) {
  int i = blockIdx.x * 256 + threadIdx.x;
  if (i >= n) return;
  int a = deg1[i], b = deg2[i];
  d1[i] = (a > 0) ? 1.0f / sqrtf((float)a) : 0.0f;
  d2[i] = (b > 0) ? 1.0f / sqrtf((float)b) : 0.0f;
}

// bucket cursors = rp at bucket starts (buckets of 256 rows)
__global__ __launch_bounds__(512) void k_bcur(const int* __restrict__ rp1, const int* __restrict__ rp2,
                                              int* __restrict__ bc1, int* __restrict__ bc2, int nb) {
  int i = threadIdx.x;
  if (i < nb) { bc1[i] = rp1[i << 8]; bc2[i] = rp2[i << 8]; }
}

// ---------------- phase A: bin edges into 256-row buckets (staged packed words) ----------------
// packed = (row & 255) << 17 | col   (requires n <= 131072)
__global__ __launch_bounds__(256) void k_bin(const int* __restrict__ rows, const int* __restrict__ cols,
                                             int* __restrict__ bcur, unsigned* __restrict__ stg,
                                             int e, int nb) {
  __shared__ int hist[512];
  __shared__ int cur[512];
  int t = threadIdx.x;
  for (int i = t; i < nb; i += 256) hist[i] = 0;
  __syncthreads();
  int e0 = blockIdx.x * 4096;
  int rr[16], cc[16];
#pragma unroll
  for (int j = 0; j < 16; ++j) {
    int idx = e0 + j * 256 + t;
    if (idx < e) {
      rr[j] = rows[idx];
      cc[j] = cols[idx];
      atomicAdd(&hist[rr[j] >> 8], 1);
    } else rr[j] = -1;
  }
  __syncthreads();
  for (int i = t; i < nb; i += 256) {
    int c = hist[i];
    cur[i] = c ? atomicAdd(&bcur[i], c) : 0;
  }
  __syncthreads();
#pragma unroll
  for (int j = 0; j < 16; ++j) {
    if (rr[j] >= 0) {
      int b = rr[j] >> 8;
      int p = atomicAdd(&cur[b], 1);
      stg[p] = ((unsigned)(rr[j] & 255) << 17) | (unsigned)cc[j];
    }
  }
}

// ---------------- phase B: per-bucket scatter into final CSR (L2-local), LDS row cursors ----------------
__global__ __launch_bounds__(256) void k_debin(const unsigned* __restrict__ stg, const int* __restrict__ rp,
                                               int* __restrict__ pos, int* __restrict__ csr, int e, int n) {
  __shared__ int cur[256];
  int b = blockIdx.x, t = threadIdx.x;
  int rbase = b << 8;
  int row_g = rbase + t;
  cur[t] = (row_g < n) ? rp[row_g] : 0;
  int start = rp[rbase];
  int next = (rbase + 256 < n) ? rp[rbase + 256] : e;
  __syncthreads();
  for (int i = start + t; i < next; i += 256) {
    unsigned pk = stg[i];
    int ro = (int)(pk >> 17);
    int col = (int)(pk & 0x1FFFFu);
    int p = atomicAdd(&cur[ro], 1);
    csr[p] = col;
  }
  __syncthreads();
  if (row_g < n) pos[row_g] = cur[t];
}

// ---------------- fused embed GEMM + 112-wide projection + d-prescale ----------------
// T layout (contiguous floats): t0[N*16] t1[N*16] t2[N*16] U1[N*32] U2[N*32]
// U1 = [t3|t5] prescaled by d1[row], U2 = [t4|t6] prescaled by d2[row]
__global__ __launch_bounds__(256) void k_embed(const float* __restrict__ x, const float* __restrict__ we,
                                               const float* __restrict__ wcl,
                                               const float* __restrict__ d1, const float* __restrict__ d2,
                                               float* __restrict__ T, int n) {
  __shared__ float pool[7168];
  __shared__ float rs[64 * 68];
  float* xs  = pool;
  float* wsm = pool + 32 * 68;

  const int t  = threadIdx.x;
  const int tx = t & 15, ty = t >> 4;
  const int br = blockIdx.x * 64;

  const int sr  = t >> 2;
  const int skc = (t & 3) * 8;
  const int xrow = min(br + sr, n - 1);
  const float* xp = x + (size_t)xrow * NFEAT;
  const int wk  = t >> 3;
  const int wc8 = (t & 7) * 8;

  float acc[4][4] = {};
  for (int k0 = 0; k0 < NFEAT; k0 += 32) {
    float4 xa = *(const float4*)(xp + k0 + skc);
    float4 xb = *(const float4*)(xp + k0 + skc + 4);
    float4 wa = *(const float4*)(we + (size_t)(k0 + wk) * HID + wc8);
    float4 wb = *(const float4*)(we + (size_t)(k0 + wk) * HID + wc8 + 4);
    __syncthreads();
    xs[(skc + 0) * 68 + sr] = xa.x;
    xs[(skc + 1) * 68 + sr] = xa.y;
    xs[(skc + 2) * 68 + sr] = xa.z;
    xs[(skc + 3) * 68 + sr] = xa.w;
    xs[(skc + 4) * 68 + sr] = xb.x;
    xs[(skc + 5) * 68 + sr] = xb.y;
    xs[(skc + 6) * 68 + sr] = xb.z;
    xs[(skc + 7) * 68 + sr] = xb.w;
    *(float4*)&wsm[wk * 68 + wc8]     = wa;
    *(float4*)&wsm[wk * 68 + wc8 + 4] = wb;
    __syncthreads();
#pragma unroll
    for (int kk = 0; kk < 32; ++kk) {
      float4 a = *(const float4*)&xs[kk * 68 + ty * 4];
      float4 b = *(const float4*)&wsm[kk * 68 + tx * 4];
      acc[0][0] += a.x * b.x; acc[0][1] += a.x * b.y; acc[0][2] += a.x * b.z; acc[0][3] += a.x * b.w;
      acc[1][0] += a.y * b.x; acc[1][1] += a.y * b.y; acc[1][2] += a.y * b.z; acc[1][3] += a.y * b.w;
      acc[2][0] += a.z * b.x; acc[2][1] += a.z * b.y; acc[2][2] += a.z * b.z; acc[2][3] += a.z * b.w;
      acc[3][0] += a.w * b.x; acc[3][1] += a.w * b.y; acc[3][2] += a.w * b.z; acc[3][3] += a.w * b.w;
    }
  }
  __syncthreads();

#pragma unroll
  for (int i = 0; i < 4; ++i) {
    float4 r4;
    r4.x = fmaxf(acc[i][0], 0.f);
    r4.y = fmaxf(acc[i][1], 0.f);
    r4.z = fmaxf(acc[i][2], 0.f);
    r4.w = fmaxf(acc[i][3], 0.f);
    *(float4*)&rs[(ty * 4 + i) * 68 + tx * 4] = r4;
  }
  const int srcblk[7] = {0, 1, 2, 3, 5, 4, 6};
  for (int i = t; i < 7168; i += 256) {
    int k = i / 112, c = i % 112;
    int p = c >> 4, cc = c & 15;
    pool[i] = wcl[(size_t)(64 * srcblk[p] + k) * NC + cc];
  }
  __syncthreads();

  const int prow = t >> 2, pcg = t & 3;
  float4 ap[7];
#pragma unroll
  for (int j = 0; j < 7; ++j) ap[j] = make_float4(0.f, 0.f, 0.f, 0.f);
  for (int k = 0; k < 64; ++k) {
    float rv = rs[prow * 68 + k];
#pragma unroll
    for (int j = 0; j < 7; ++j) {
      float4 w4 = *(const float4*)&pool[k * 112 + pcg * 28 + j * 4];
      ap[j].x += rv * w4.x; ap[j].y += rv * w4.y; ap[j].z += rv * w4.z; ap[j].w += rv * w4.w;
    }
  }
  int gr = br + prow;
  if (gr < n) {
    size_t sn = (size_t)n;
    float d1v = d1[gr], d2v = d2[gr];
#pragma unroll
    for (int j = 0; j < 7; ++j) {
      int c = pcg * 28 + j * 4;
      int p = c >> 4, cc = c & 15;
      float s = (p < 3) ? 1.0f : ((p < 5) ? d1v : d2v);
      float4 v = ap[j];
      v.x *= s; v.y *= s; v.z *= s; v.w *= s;
      size_t o;
      if (p < 3)      o = (size_t)p * 16 * sn + (size_t)gr * 16 + cc;
      else if (p < 5) o = 48 * sn + (size_t)gr * 32 + ((p == 4) ? 16 : 0) + cc;
      else            o = 80 * sn + (size_t)gr * 32 + ((p == 6) ? 16 : 0) + cc;
      *(float4*)(T + o) = v;
    }
  }
}

// ---------------- CSR SpMM (binary A, pre-scaled src): dst = d[row] * sum_{c} src[c] ----------------
template <int L>
__global__ __launch_bounds__(256) void k_spmm(const int* __restrict__ rp, const int* __restrict__ re,
                                              const int* __restrict__ cols, const float* __restrict__ d,
                                              const float* __restrict__ src, float* __restrict__ dst, int n) {
  int t = blockIdx.x * 256 + threadIdx.x;
  int row = t / L;
  if (row >= n) return;
  int sub = t % L;
  int e = rp[row], end = re[row];
  const float4* s4 = (const float4*)src;
  float4 acc = make_float4(0.f, 0.f, 0.f, 0.f);
  for (; e < end; ++e) {
    int c = cols[e];
    float4 g = s4[(size_t)c * L + sub];
    acc.x += g.x; acc.y += g.y; acc.z += g.z; acc.w += g.w;
  }
  float s = d[row];
  acc.x *= s; acc.y *= s; acc.z *= s; acc.w *= s;
  ((float4*)dst)[(size_t)row * L + sub] = acc;
}

// ---------------- combine: p = d1*(t1 + P1.lo + P2.lo) ; q = d2*(t2 + P1.hi + P2.hi) ----------------
__global__ __launch_bounds__(256) void k_combine(float* __restrict__ t1, float* __restrict__ t2,
                                                 const float* __restrict__ P1, const float* __restrict__ P2,
                                                 const float* __restrict__ d1, const float* __restrict__ d2,
                                                 int n) {
  int t = blockIdx.x * 256 + threadIdx.x;
  if (t >= n * 4) return;
  int row = t >> 2, c = t & 3;
  float s1 = d1[row], s2 = d2[row];
  float4* T1 = (float4*)t1;
  float4* T2 = (float4*)t2;
  const float4* p1 = (const float4*)P1;
  const float4* p2 = (const float4*)P2;
  float4 a = T1[t], u = p1[(size_t)row * 8 + c], w = p2[(size_t)row * 8 + c];
  a.x = (a.x + u.x + w.x) * s1; a.y = (a.y + u.y + w.y) * s1;
  a.z = (a.z + u.z + w.z) * s1; a.w = (a.w + u.w + w.w) * s1;
  T1[t] = a;
  float4 b = T2[t];
  u = p1[(size_t)row * 8 + 4 + c]; w = p2[(size_t)row * 8 + 4 + c];
  b.x = (b.x + u.x + w.x) * s2; b.y = (b.y + u.y + w.y) * s2;
  b.z = (b.z + u.z + w.z) * s2; b.w = (b.w + u.w + w.w) * s2;
  T2[t] = b;
}

// ---------------- final: out = log_softmax(t0 + zA + zB) ----------------
__global__ __launch_bounds__(256) void k_final(const float* __restrict__ t0, const float* __restrict__ zA,
                                               const float* __restrict__ zB, float* __restrict__ out, int n) {
  int row = blockIdx.x * 256 + threadIdx.x;
  if (row >= n) return;
  const float4* a4 = (const float4*)t0;
  const float4* b4 = (const float4*)zA;
  const float4* c4 = (const float4*)zB;
  float z[16];
#pragma unroll
  for (int j = 0; j < 4; ++j) {
    float4 a = a4[(size_t)row * 4 + j], b = b4[(size_t)row * 4 + j], c = c4[(size_t)row * 4 + j];
    z[j * 4 + 0] = a.x + b.x + c.x;
    z[j * 4 + 1] = a.y + b.y + c.y;
    z[j * 4 + 2] = a.z + b.z + c.z;
    z[j * 4 + 3] = a.w + b.w + c.w;
  }
  float m = z[0];
#pragma unroll
  for (int i = 1; i < 16; ++i) m = fmaxf(m, z[i]);
  float s = 0.f;
#pragma unroll
  for (int i = 0; i < 16; ++i) s += expf(z[i] - m);
  float lg = m + logf(s);
  float4* o4 = (float4*)out;
#pragma unroll
  for (int j = 0; j < 4; ++j) {
    float4 o;
    o.x = z[j * 4 + 0] - lg; o.y = z[j * 4 + 1] - lg;
    o.z = z[j * 4 + 2] - lg; o.w = z[j * 4 + 3] - lg;
    o4[(size_t)row * 4 + j] = o;
  }
}

extern "C" void kernel_launch(void* const* d_in, const int* in_sizes, int n_in,
                              void* d_out, int out_size, void* d_ws, size_t ws_size,
                              hipStream_t stream) {
  const float* x   = (const float*)d_in[0];
  const int*   a1i = (const int*)d_in[1];
  const int*   a2i = (const int*)d_in[3];
  const float* we  = (const float*)d_in[5];
  const float* wcl = (const float*)d_in[6];
  float* out = (float*)d_out;

  const int n  = in_sizes[0] / NFEAT;
  const int e1 = in_sizes[2];
  const int e2 = in_sizes[4];
  const int nb = (n + 255) / 256;   // <= 512 (requires n <= 131072)

  char* ws = (char*)d_ws;
  size_t off = 0;
  auto alloc = [&](size_t bytes) -> void* {
    void* p = ws + off;
    off += (bytes + 255) & ~(size_t)255;
    return p;
  };
  // T block contiguous: t0,t1,t2,U1,U2
  float* t0 = (float*)alloc((size_t)n * 16 * 4);
  float* t1 = (float*)alloc((size_t)n * 16 * 4);
  float* t2 = (float*)alloc((size_t)n * 16 * 4);
  float* U1 = (float*)alloc((size_t)n * 32 * 4);
  float* U2 = (float*)alloc((size_t)n * 32 * 4);
  float* P1 = (float*)alloc((size_t)n * 32 * 4);
  float* P2 = (float*)alloc((size_t)n * 32 * 4);
  int* deg1 = (int*)alloc((size_t)n * 4);
  int* rp1  = (int*)alloc((size_t)n * 4);
  int* pos1 = (int*)alloc((size_t)n * 4);
  int* deg2 = (int*)alloc((size_t)n * 4);
  int* rp2  = (int*)alloc((size_t)n * 4);
  int* pos2 = (int*)alloc((size_t)n * 4);
  float* d1 = (float*)alloc((size_t)n * 4);
  float* d2 = (float*)alloc((size_t)n * 4);
  int*      col1 = (int*)alloc((size_t)e1 * 4);
  int*      col2 = (int*)alloc((size_t)e2 * 4);
  unsigned* stg1 = (unsigned*)alloc((size_t)e1 * 4);
  unsigned* stg2 = (unsigned*)alloc((size_t)e2 * 4);
  int* bs1  = (int*)alloc(1024);
  int* bsx1 = (int*)alloc(1024);
  int* bs2  = (int*)alloc(1024);
  int* bsx2 = (int*)alloc(1024);
  int* bc1  = (int*)alloc(2048);
  int* bc2  = (int*)alloc(2048);
  float* zA = U1;  // U1/U2 dead after inner spmm passes
  float* zB = U2;

  (void)ws_size; (void)n_in; (void)out_size;

  hipMemsetAsync(deg1, 0, (size_t)n * 4, stream);
  hipMemsetAsync(deg2, 0, (size_t)n * 4, stream);

  k_hist<<<(e1 + 255) / 256, 256, 0, stream>>>(a1i, deg1, e1);
  k_hist<<<(e2 + 255) / 256, 256, 0, stream>>>(a2i, deg2, e2);

  int nchunk = (n + 2047) / 2048;
  k_scan1<<<nchunk, 256, 0, stream>>>(deg1, rp1, bs1, n);
  k_scan1<<<nchunk, 256, 0, stream>>>(deg2, rp2, bs2, n);
  k_scan1<<<1, 256, 0, stream>>>(bs1, bsx1, nullptr, nchunk);
  k_scan1<<<1, 256, 0, stream>>>(bs2, bsx2, nullptr, nchunk);
  k_scanadd<<<(n + 255) / 256, 256, 0, stream>>>(rp1, bsx1, n);
  k_scanadd<<<(n + 255) / 256, 256, 0, stream>>>(rp2, bsx2, n);

  k_rsqrt<<<(n + 255) / 256, 256, 0, stream>>>(deg1, deg2, d1, d2, n);
  k_bcur<<<1, 512, 0, stream>>>(rp1, rp2, bc1, bc2, nb);

  // phase A: bin by row>>8 into staged packed words
  k_bin<<<(e1 + 4095) / 4096, 256, 0, stream>>>(a1i, a1i + e1, bc1, stg1, e1, nb);
  k_bin<<<(e2 + 4095) / 4096, 256, 0, stream>>>(a2i, a2i + e2, bc2, stg2, e2, nb);

  // phase B: per-bucket L2-local scatter into CSR; emits per-row ends (pos)
  k_debin<<<nb, 256, 0, stream>>>(stg1, rp1, pos1, col1, e1, n);
  k_debin<<<nb, 256, 0, stream>>>(stg2, rp2, pos2, col2, e2, n);

  k_embed<<<(n + 63) / 64, 256, 0, stream>>>(x, we, wcl, d1, d2, t0, n);

  // inner passes (width 32): P1 = d1*(A1 @ U1), P2 = d2*(A2 @ U2)
  k_spmm<8><<<(n * 8 + 255) / 256, 256, 0, stream>>>(rp1, pos1, col1, d1, U1, P1, n);
  k_spmm<8><<<(n * 8 + 255) / 256, 256, 0, stream>>>(rp2, pos2, col2, d2, U2, P2, n);

  // combine into outer-pass sources (pre-scaled)
  k_combine<<<(n * 4 + 255) / 256, 256, 0, stream>>>(t1, t2, P1, P2, d1, d2, n);

  // outer passes (width 16): zA = d1*(A1 @ p), zB = d2*(A2 @ q)
  k_spmm<4><<<(n * 4 + 255) / 256, 256, 0, stream>>>(rp1, pos1, col1, d1, t1, zA, n);
  k_spmm<4><<<(n * 4 + 255) / 256, 256, 0, stream>>>(rp2, pos2, col2, d2, t2, zB, n);

  k_final<<<(n + 255) / 256, 256, 0, stream>>>(t0, zA, zB, out, n);
}

// Round 3
// 1608.151 us; speedup vs baseline: 1.4405x; 1.0832x over previous
//
#include <hip/hip_runtime.h>

constexpr int NFEAT = 1024;
constexpr int HID   = 64;
constexpr int NC    = 16;

typedef __attribute__((ext_vector_type(8))) short bf16x8;
typedef __attribute__((ext_vector_type(4))) float f32x4;

__device__ inline unsigned short f2bf(float f) {
  unsigned u = __float_as_uint(f);
  unsigned r = u + 0x7FFFu + ((u >> 16) & 1u);
  return (unsigned short)(r >> 16);
}

// ---------------- degree histogram ----------------
__global__ __launch_bounds__(256) void k_hist(const int* __restrict__ rows, int* __restrict__ deg, int e) {
  int i = blockIdx.x * 256 + threadIdx.x;
  if (i < e) atomicAdd(&deg[rows[i]], 1);
}

// exclusive scan of chunks of 2048; block sums to bsum (if non-null)
__global__ __launch_bounds__(256) void k_scan1(const int* __restrict__ in, int* __restrict__ out,
                                               int* __restrict__ bsum, int n) {
  __shared__ int sh[256];
  int base = blockIdx.x * 2048 + threadIdx.x * 8;
  int v[8]; int s = 0;
#pragma unroll
  for (int j = 0; j < 8; ++j) { int idx = base + j; v[j] = (idx < n) ? in[idx] : 0; s += v[j]; }
  sh[threadIdx.x] = s; __syncthreads();
  for (int off = 1; off < 256; off <<= 1) {
    int x = (threadIdx.x >= off) ? sh[threadIdx.x - off] : 0;
    __syncthreads();
    sh[threadIdx.x] += x;
    __syncthreads();
  }
  int run = (threadIdx.x > 0) ? sh[threadIdx.x - 1] : 0;
  if (bsum != nullptr && threadIdx.x == 255) bsum[blockIdx.x] = sh[255];
#pragma unroll
  for (int j = 0; j < 8; ++j) { int idx = base + j; if (idx < n) out[idx] = run; run += v[j]; }
}

__global__ __launch_bounds__(256) void k_scanadd(int* __restrict__ rp, const int* __restrict__ bs, int n) {
  int i = blockIdx.x * 256 + threadIdx.x;
  if (i < n) rp[i] += bs[i >> 11];
}

// d = deg > 0 ? deg^-1/2 : 0
__global__ __launch_bounds__(256) void k_rsqrt(const int* __restrict__ deg1, const int* __restrict__ deg2,
                                               float* __restrict__ d1, float* __restrict__ d2, int n) {
  int i = blockIdx.x * 256 + threadIdx.x;
  if (i >= n) return;
  int a = deg1[i], b = deg2[i];
  d1[i] = (a > 0) ? 1.0f / sqrtf((float)a) : 0.0f;
  d2[i] = (b > 0) ? 1.0f / sqrtf((float)b) : 0.0f;
}

// bucket cursors = rp at bucket starts (buckets of 256 rows)
__global__ __launch_bounds__(512) void k_bcur(const int* __restrict__ rp1, const int* __restrict__ rp2,
                                              int* __restrict__ bc1, int* __restrict__ bc2, int nb) {
  int i = threadIdx.x;
  if (i < nb) { bc1[i] = rp1[i << 8]; bc2[i] = rp2[i << 8]; }
}

// ---------------- phase A: bin edges into 256-row buckets (staged packed words) ----------------
// packed = (row & 255) << 17 | col   (requires n <= 131072)
__global__ __launch_bounds__(256) void k_bin(const int* __restrict__ rows, const int* __restrict__ cols,
                                             int* __restrict__ bcur, unsigned* __restrict__ stg,
                                             int e, int nb) {
  __shared__ int hist[512];
  __shared__ int cur[512];
  int t = threadIdx.x;
  for (int i = t; i < nb; i += 256) hist[i] = 0;
  __syncthreads();
  int e0 = blockIdx.x * 4096;
  int rr[16], cc[16];
#pragma unroll
  for (int j = 0; j < 16; ++j) {
    int idx = e0 + j * 256 + t;
    if (idx < e) {
      rr[j] = rows[idx];
      cc[j] = cols[idx];
      atomicAdd(&hist[rr[j] >> 8], 1);
    } else rr[j] = -1;
  }
  __syncthreads();
  for (int i = t; i < nb; i += 256) {
    int c = hist[i];
    cur[i] = c ? atomicAdd(&bcur[i], c) : 0;
  }
  __syncthreads();
#pragma unroll
  for (int j = 0; j < 16; ++j) {
    if (rr[j] >= 0) {
      int b = rr[j] >> 8;
      int p = atomicAdd(&cur[b], 1);
      stg[p] = ((unsigned)(rr[j] & 255) << 17) | (unsigned)cc[j];
    }
  }
}

// ---------------- phase B: per-bucket scatter into final CSR (L2-local), LDS row cursors ----------------
__global__ __launch_bounds__(256) void k_debin(const unsigned* __restrict__ stg, const int* __restrict__ rp,
                                               int* __restrict__ pos, int* __restrict__ csr, int e, int n) {
  __shared__ int cur[256];
  int b = blockIdx.x, t = threadIdx.x;
  int rbase = b << 8;
  int row_g = rbase + t;
  cur[t] = (row_g < n) ? rp[row_g] : 0;
  int start = rp[rbase];
  int next = (rbase + 256 < n) ? rp[rbase + 256] : e;
  __syncthreads();
  for (int i = start + t; i < next; i += 256) {
    unsigned pk = stg[i];
    int ro = (int)(pk >> 17);
    int col = (int)(pk & 0x1FFFFu);
    int p = atomicAdd(&cur[ro], 1);
    csr[p] = col;
  }
  __syncthreads();
  if (row_g < n) pos[row_g] = cur[t];
}

// ---------------- fused embed GEMM (bf16 MFMA) + 112-wide projection + d-prescale ----------------
// T layout (contiguous floats): t0[N*16] t1[N*16] t2[N*16] U1[N*32] U2[N*32]
// U1 = [t3|t5] prescaled by d1[row], U2 = [t4|t6] prescaled by d2[row]
__global__ __launch_bounds__(256) void k_embed(const float* __restrict__ x, const float* __restrict__ we,
                                               const float* __restrict__ wcl,
                                               const float* __restrict__ d1, const float* __restrict__ d2,
                                               float* __restrict__ T, int n) {
  __shared__ float pool[7168];          // phase1: xs bf16[64][72] + wsb bf16[64][72]; phase2: wall f32[64][112]
  __shared__ float rs[64 * 68];
  unsigned short* xs  = (unsigned short*)pool;           // A tile, [row][k] bf16, stride 72
  unsigned short* wsb = (unsigned short*)(pool + 2304);  // B tile transposed, [n][k] bf16, stride 72

  const int t    = threadIdx.x;
  const int w    = t >> 6;        // wave 0..3
  const int l    = t & 63;
  const int quad = l >> 4;
  const int lr   = l & 15;
  const int br   = blockIdx.x * 64;

  // x staging: thread t -> row t>>2, 4x float4 at col (t&3)*4 + j*16 (64B contiguous per 4 lanes)
  const int sxr = t >> 2;
  const int sxc = (t & 3) * 4;
  const int xrow = min(br + sxr, n - 1);
  const float* xp = x + (size_t)xrow * NFEAT;
  // we staging (transpose): thread t -> n = t&63, k rows (t>>6)*4 + i + p*16
  const int swn = t & 63;
  const int swk = (t >> 6) * 4;

  f32x4 acc[4];
#pragma unroll
  for (int i = 0; i < 4; ++i) acc[i] = (f32x4){0.f, 0.f, 0.f, 0.f};

  for (int kc = 0; kc < NFEAT; kc += 64) {
    float4 xv[4];
#pragma unroll
    for (int j = 0; j < 4; ++j) xv[j] = *(const float4*)(xp + kc + j * 16 + sxc);
    float wv[16];
#pragma unroll
    for (int p = 0; p < 4; ++p)
#pragma unroll
      for (int i = 0; i < 4; ++i)
        wv[p * 4 + i] = we[(size_t)(kc + p * 16 + swk + i) * HID + swn];
    __syncthreads();   // all waves done reading fragments of previous chunk
#pragma unroll
    for (int j = 0; j < 4; ++j) {
      ushort4 u;
      u.x = f2bf(xv[j].x); u.y = f2bf(xv[j].y); u.z = f2bf(xv[j].z); u.w = f2bf(xv[j].w);
      *(ushort4*)&xs[sxr * 72 + j * 16 + sxc] = u;
    }
#pragma unroll
    for (int p = 0; p < 4; ++p) {
      ushort4 u;
      u.x = f2bf(wv[p * 4 + 0]); u.y = f2bf(wv[p * 4 + 1]);
      u.z = f2bf(wv[p * 4 + 2]); u.w = f2bf(wv[p * 4 + 3]);
      *(ushort4*)&wsb[swn * 72 + p * 16 + swk] = u;
    }
    __syncthreads();
#pragma unroll
    for (int ks = 0; ks < 2; ++ks) {
      bf16x8 af = *(const bf16x8*)&xs[(w * 16 + lr) * 72 + ks * 32 + quad * 8];
#pragma unroll
      for (int nt = 0; nt < 4; ++nt) {
        bf16x8 bfr = *(const bf16x8*)&wsb[(nt * 16 + lr) * 72 + ks * 32 + quad * 8];
        acc[nt] = __builtin_amdgcn_mfma_f32_16x16x32_bf16(af, bfr, acc[nt], 0, 0, 0);
      }
    }
  }
  __syncthreads();

  // relu -> rs; C/D layout: col = lane&15, row = quad*4 + reg
#pragma unroll
  for (int nt = 0; nt < 4; ++nt)
#pragma unroll
    for (int r = 0; r < 4; ++r)
      rs[(w * 16 + quad * 4 + r) * 68 + nt * 16 + lr] = fmaxf(acc[nt][r], 0.f);

  // wall load, permuted block order [t0 t1 t2 t3 t5 t4 t6]
  const int srcblk[7] = {0, 1, 2, 3, 5, 4, 6};
  for (int i = t; i < 7168; i += 256) {
    int k = i / 112, c = i % 112;
    int p = c >> 4, cc = c & 15;
    pool[i] = wcl[(size_t)(64 * srcblk[p] + k) * NC + cc];
  }
  __syncthreads();

  const int prow = t >> 2, pcg = t & 3;
  float4 ap[7];
#pragma unroll
  for (int j = 0; j < 7; ++j) ap[j] = make_float4(0.f, 0.f, 0.f, 0.f);
  for (int k = 0; k < 64; ++k) {
    float rv = rs[prow * 68 + k];
#pragma unroll
    for (int j = 0; j < 7; ++j) {
      float4 w4 = *(const float4*)&pool[k * 112 + pcg * 28 + j * 4];
      ap[j].x += rv * w4.x; ap[j].y += rv * w4.y; ap[j].z += rv * w4.z; ap[j].w += rv * w4.w;
    }
  }
  int gr = br + prow;
  if (gr < n) {
    size_t sn = (size_t)n;
    float d1v = d1[gr], d2v = d2[gr];
#pragma unroll
    for (int j = 0; j < 7; ++j) {
      int c = pcg * 28 + j * 4;
      int p = c >> 4, cc = c & 15;
      float s = (p < 3) ? 1.0f : ((p < 5) ? d1v : d2v);
      float4 v = ap[j];
      v.x *= s; v.y *= s; v.z *= s; v.w *= s;
      size_t o;
      if (p < 3)      o = (size_t)p * 16 * sn + (size_t)gr * 16 + cc;
      else if (p < 5) o = 48 * sn + (size_t)gr * 32 + ((p == 4) ? 16 : 0) + cc;
      else            o = 80 * sn + (size_t)gr * 32 + ((p == 6) ? 16 : 0) + cc;
      *(float4*)(T + o) = v;
    }
  }
}

// ---------------- CSR SpMM (binary A, pre-scaled src): dst = d[row] * sum_{c} src[c] ----------------
template <int L>
__global__ __launch_bounds__(256) void k_spmm(const int* __restrict__ rp, const int* __restrict__ re,
                                              const int* __restrict__ cols, const float* __restrict__ d,
                                              const float* __restrict__ src, float* __restrict__ dst, int n) {
  int t = blockIdx.x * 256 + threadIdx.x;
  int row = t / L;
  if (row >= n) return;
  int sub = t % L;
  int e = rp[row], end = re[row];
  const float4* s4 = (const float4*)src;
  float4 acc = make_float4(0.f, 0.f, 0.f, 0.f);
  for (; e < end; ++e) {
    int c = cols[e];
    float4 g = s4[(size_t)c * L + sub];
    acc.x += g.x; acc.y += g.y; acc.z += g.z; acc.w += g.w;
  }
  float s = d[row];
  acc.x *= s; acc.y *= s; acc.z *= s; acc.w *= s;
  ((float4*)dst)[(size_t)row * L + sub] = acc;
}

// ---------------- combine: p = d1*(t1 + P1.lo + P2.lo) ; q = d2*(t2 + P1.hi + P2.hi) ----------------
__global__ __launch_bounds__(256) void k_combine(float* __restrict__ t1, float* __restrict__ t2,
                                                 const float* __restrict__ P1, const float* __restrict__ P2,
                                                 const float* __restrict__ d1, const float* __restrict__ d2,
                                                 int n) {
  int t = blockIdx.x * 256 + threadIdx.x;
  if (t >= n * 4) return;
  int row = t >> 2, c = t & 3;
  float s1 = d1[row], s2 = d2[row];
  float4* T1 = (float4*)t1;
  float4* T2 = (float4*)t2;
  const float4* p1 = (const float4*)P1;
  const float4* p2 = (const float4*)P2;
  float4 a = T1[t], u = p1[(size_t)row * 8 + c], w = p2[(size_t)row * 8 + c];
  a.x = (a.x + u.x + w.x) * s1; a.y = (a.y + u.y + w.y) * s1;
  a.z = (a.z + u.z + w.z) * s1; a.w = (a.w + u.w + w.w) * s1;
  T1[t] = a;
  float4 b = T2[t];
  u = p1[(size_t)row * 8 + 4 + c]; w = p2[(size_t)row * 8 + 4 + c];
  b.x = (b.x + u.x + w.x) * s2; b.y = (b.y + u.y + w.y) * s2;
  b.z = (b.z + u.z + w.z) * s2; b.w = (b.w + u.w + w.w) * s2;
  T2[t] = b;
}

// ---------------- final: out = log_softmax(t0 + zA + zB) ----------------
__global__ __launch_bounds__(256) void k_final(const float* __restrict__ t0, const float* __restrict__ zA,
                                               const float* __restrict__ zB, float* __restrict__ out, int n) {
  int row = blockIdx.x * 256 + threadIdx.x;
  if (row >= n) return;
  const float4* a4 = (const float4*)t0;
  const float4* b4 = (const float4*)zA;
  const float4* c4 = (const float4*)zB;
  float z[16];
#pragma unroll
  for (int j = 0; j < 4; ++j) {
    float4 a = a4[(size_t)row * 4 + j], b = b4[(size_t)row * 4 + j], c = c4[(size_t)row * 4 + j];
    z[j * 4 + 0] = a.x + b.x + c.x;
    z[j * 4 + 1] = a.y + b.y + c.y;
    z[j * 4 + 2] = a.z + b.z + c.z;
    z[j * 4 + 3] = a.w + b.w + c.w;
  }
  float m = z[0];
#pragma unroll
  for (int i = 1; i < 16; ++i) m = fmaxf(m, z[i]);
  float s = 0.f;
#pragma unroll
  for (int i = 0; i < 16; ++i) s += expf(z[i] - m);
  float lg = m + logf(s);
  float4* o4 = (float4*)out;
#pragma unroll
  for (int j = 0; j < 4; ++j) {
    float4 o;
    o.x = z[j * 4 + 0] - lg; o.y = z[j * 4 + 1] - lg;
    o.z = z[j * 4 + 2] - lg; o.w = z[j * 4 + 3] - lg;
    o4[(size_t)row * 4 + j] = o;
  }
}

extern "C" void kernel_launch(void* const* d_in, const int* in_sizes, int n_in,
                              void* d_out, int out_size, void* d_ws, size_t ws_size,
                              hipStream_t stream) {
  const float* x   = (const float*)d_in[0];
  const int*   a1i = (const int*)d_in[1];
  const int*   a2i = (const int*)d_in[3];
  const float* we  = (const float*)d_in[5];
  const float* wcl = (const float*)d_in[6];
  float* out = (float*)d_out;

  const int n  = in_sizes[0] / NFEAT;
  const int e1 = in_sizes[2];
  const int e2 = in_sizes[4];
  const int nb = (n + 255) / 256;   // <= 512 (requires n <= 131072)

  char* ws = (char*)d_ws;
  size_t off = 0;
  auto alloc = [&](size_t bytes) -> void* {
    void* p = ws + off;
    off += (bytes + 255) & ~(size_t)255;
    return p;
  };
  // T block contiguous: t0,t1,t2,U1,U2
  float* t0 = (float*)alloc((size_t)n * 16 * 4);
  float* t1 = (float*)alloc((size_t)n * 16 * 4);
  float* t2 = (float*)alloc((size_t)n * 16 * 4);
  float* U1 = (float*)alloc((size_t)n * 32 * 4);
  float* U2 = (float*)alloc((size_t)n * 32 * 4);
  float* P1 = (float*)alloc((size_t)n * 32 * 4);
  float* P2 = (float*)alloc((size_t)n * 32 * 4);
  int* deg1 = (int*)alloc((size_t)n * 4);
  int* rp1  = (int*)alloc((size_t)n * 4);
  int* pos1 = (int*)alloc((size_t)n * 4);
  int* deg2 = (int*)alloc((size_t)n * 4);
  int* rp2  = (int*)alloc((size_t)n * 4);
  int* pos2 = (int*)alloc((size_t)n * 4);
  float* d1 = (float*)alloc((size_t)n * 4);
  float* d2 = (float*)alloc((size_t)n * 4);
  int*      col1 = (int*)alloc((size_t)e1 * 4);
  int*      col2 = (int*)alloc((size_t)e2 * 4);
  unsigned* stg1 = (unsigned*)alloc((size_t)e1 * 4);
  unsigned* stg2 = (unsigned*)alloc((size_t)e2 * 4);
  int* bs1  = (int*)alloc(1024);
  int* bsx1 = (int*)alloc(1024);
  int* bs2  = (int*)alloc(1024);
  int* bsx2 = (int*)alloc(1024);
  int* bc1  = (int*)alloc(2048);
  int* bc2  = (int*)alloc(2048);
  float* zA = U1;  // U1/U2 dead after inner spmm passes
  float* zB = U2;

  (void)ws_size; (void)n_in; (void)out_size;

  hipMemsetAsync(deg1, 0, (size_t)n * 4, stream);
  hipMemsetAsync(deg2, 0, (size_t)n * 4, stream);

  k_hist<<<(e1 + 255) / 256, 256, 0, stream>>>(a1i, deg1, e1);
  k_hist<<<(e2 + 255) / 256, 256, 0, stream>>>(a2i, deg2, e2);

  int nchunk = (n + 2047) / 2048;
  k_scan1<<<nchunk, 256, 0, stream>>>(deg1, rp1, bs1, n);
  k_scan1<<<nchunk, 256, 0, stream>>>(deg2, rp2, bs2, n);
  k_scan1<<<1, 256, 0, stream>>>(bs1, bsx1, nullptr, nchunk);
  k_scan1<<<1, 256, 0, stream>>>(bs2, bsx2, nullptr, nchunk);
  k_scanadd<<<(n + 255) / 256, 256, 0, stream>>>(rp1, bsx1, n);
  k_scanadd<<<(n + 255) / 256, 256, 0, stream>>>(rp2, bsx2, n);

  k_rsqrt<<<(n + 255) / 256, 256, 0, stream>>>(deg1, deg2, d1, d2, n);
  k_bcur<<<1, 512, 0, stream>>>(rp1, rp2, bc1, bc2, nb);

  // phase A: bin by row>>8 into staged packed words
  k_bin<<<(e1 + 4095) / 4096, 256, 0, stream>>>(a1i, a1i + e1, bc1, stg1, e1, nb);
  k_bin<<<(e2 + 4095) / 4096, 256, 0, stream>>>(a2i, a2i + e2, bc2, stg2, e2, nb);

  // phase B: per-bucket L2-local scatter into CSR; emits per-row ends (pos)
  k_debin<<<nb, 256, 0, stream>>>(stg1, rp1, pos1, col1, e1, n);
  k_debin<<<nb, 256, 0, stream>>>(stg2, rp2, pos2, col2, e2, n);

  k_embed<<<(n + 63) / 64, 256, 0, stream>>>(x, we, wcl, d1, d2, t0, n);

  // inner passes (width 32): P1 = d1*(A1 @ U1), P2 = d2*(A2 @ U2)
  k_spmm<8><<<(n * 8 + 255) / 256, 256, 0, stream>>>(rp1, pos1, col1, d1, U1, P1, n);
  k_spmm<8><<<(n * 8 + 255) / 256, 256, 0, stream>>>(rp2, pos2, col2, d2, U2, P2, n);

  // combine into outer-pass sources (pre-scaled)
  k_combine<<<(n * 4 + 255) / 256, 256, 0, stream>>>(t1, t2, P1, P2, d1, d2, n);

  // outer passes (width 16): zA = d1*(A1 @ p), zB = d2*(A2 @ q)
  k_spmm<4><<<(n * 4 + 255) / 256, 256, 0, stream>>>(rp1, pos1, col1, d1, t1, zA, n);
  k_spmm<4><<<(n * 4 + 255) / 256, 256, 0, stream>>>(rp2, pos2, col2, d2, t2, zB, n);

  k_final<<<(n + 255) / 256, 256, 0, stream>>>(t0, zA, zB, out, n);
}